// Round 5
// baseline (66.901 us; speedup 1.0000x reference)
//
#include <hip/hip_runtime.h>
#include <math.h>

#define BB 8
#define SS 8192
#define DD 64
#define DM 1024
#define EPSF 1e-8f
#define NROWS (BB * SS)                 // 65536 rows
#define YQ_ELEMS ((size_t)NROWS * DM)   // yQ elements; xi follows in d_out

typedef float floatx4 __attribute__((ext_vector_type(4)));

// ws float layout (final vectors, 16 KB):
//   UP[1024] | UN[1024] | CP[1024]=b2+DP | CN[1024]=b2+DN

// ---------------- Kernel P: final per-n vectors (64 blocks) ----------------
__global__ __launch_bounds__(256) void qac_part(
    const float* __restrict__ W1, const float* __restrict__ b1,
    const float* __restrict__ W2, const float* __restrict__ b2,
    float* __restrict__ ws) {
  __shared__ float red[4][16][16];
  const int t = threadIdx.x;
  const int tn = t & 15;   // col within block's 16-col strip
  const int tm = t >> 4;   // 0..15 m-chunk (64 m each)
  const int nb = blockIdx.x;
  const int n = nb * 16 + tn;

  float up = 0.f, un = 0.f, dp = 0.f, dn = 0.f;
  const int m0 = tm * 64;
#pragma unroll 8
  for (int i = 0; i < 64; ++i) {
    const int m = m0 + i;
    const float w1 = W1[m];
    const float bv = b1[m];
    const float w2 = W2[(size_t)m * DM + n];
    const float wp = w1 > 0.f ? w1 : 0.f;
    const float wn = w1 < 0.f ? w1 : 0.f;
    const float bp = w1 > 0.f ? bv : 0.f;
    const float bn = w1 < 0.f ? bv : 0.f;
    up = fmaf(wp, w2, up);
    un = fmaf(wn, w2, un);
    dp = fmaf(bp, w2, dp);
    dn = fmaf(bn, w2, dn);
  }
  red[0][tm][tn] = up;
  red[1][tm][tn] = un;
  red[2][tm][tn] = dp;
  red[3][tm][tn] = dn;
  __syncthreads();
  if (t < 64) {
    const int q = t >> 4;        // which vector
    const int col = t & 15;
    float s = 0.f;
#pragma unroll
    for (int j = 0; j < 16; ++j) s += red[q][j][col];
    const int n2 = nb * 16 + col;
    if (q < 2) {
      ws[q * DM + n2] = s;             // UP / UN
    } else {
      ws[q * DM + n2] = b2[n2] + s;    // CP / CN (b2 folded)
    }
  }
}

// ---------------- Kernel F: fused xi + yQ stream ----------------
// Grid 1024 x 256: 64 rows/block. Phase 1: xi (4 passes x 16 rows,
// 16 lanes/row). Phase 2: 256 KB contiguous nt-stores.
__global__ __launch_bounds__(256) void qac_fused(
    const float* __restrict__ psiQ, const float* __restrict__ psiK,
    const float* __restrict__ psiV, const float* __restrict__ ws,
    float* __restrict__ out) {
  __shared__ float xis[64];
  const int t = threadIdx.x;
  const int r0 = blockIdx.x * 64;
  const int g = t & 15;
  const int grp = t >> 4;

  // issue per-n vector loads early (L2-resident, 16 KB)
  const float4 up = ((const float4*)(ws))[t];
  const float4 un = ((const float4*)(ws + DM))[t];
  const float4 cp = ((const float4*)(ws + 2 * DM))[t];
  const float4 cn = ((const float4*)(ws + 3 * DM))[t];

  // ---- phase 1: xi for 64 rows ----
#pragma unroll
  for (int pass = 0; pass < 4; ++pass) {
    const int row = r0 + pass * 16 + grp;
    const floatx4 q = __builtin_nontemporal_load(
        (const floatx4*)(psiQ + (size_t)row * DD) + g);
    const floatx4 k = __builtin_nontemporal_load(
        (const floatx4*)(psiK + (size_t)row * DD) + g);
    const floatx4 v = __builtin_nontemporal_load(
        (const floatx4*)(psiV + (size_t)row * DD) + g);

    float sq = q.x + q.y + q.z + q.w;
    float sq2 = q.x * q.x + q.y * q.y + q.z * q.z + q.w * q.w;
    float sk2 = k.x * k.x + k.y * k.y + k.z * k.z + k.w * k.w;
    const float v2 = v.x * v.x + v.y * v.y + v.z * v.z + v.w * v.w;
    float va = (g < 8) ? v2 : 0.f;  // d in [0,32)
    float vb = (g < 8) ? 0.f : v2;  // d in [32,64)
    const float k0 = k.x;           // k[row][0] on lane g==0

#pragma unroll
    for (int m = 1; m < 16; m <<= 1) {
      sq += __shfl_xor(sq, m);
      sq2 += __shfl_xor(sq2, m);
      sk2 += __shfl_xor(sk2, m);
      va += __shfl_xor(va, m);
      vb += __shfl_xor(vb, m);
    }
    if (g == 0) {
      const float nq = sqrtf(sq2) + EPSF;
      const float nk = sqrtf(sk2) + EPSF;
      const float nv = sqrtf(va + vb) + EPSF;
      const float sqn = sq / nq;
      const float k0n = k0 / nk;
      const float att = sqn * sqn * k0n * k0n * (1.0f / 64.0f);
      const float vexp = (va - vb) / (nv * nv);
      xis[pass * 16 + grp] = att * vexp;
    }
  }
  __syncthreads();

  // xi output
  if (t < 64) out[YQ_ELEMS + r0 + t] = xis[t];

  // ---- phase 2: yQ stream ----
#pragma unroll 8
  for (int r = 0; r < 64; ++r) {
    const float xi = xis[r];
    const bool pos = xi > 0.f;
    floatx4 o;
    o.x = fmaf(xi, pos ? up.x : un.x, pos ? cp.x : cn.x);
    o.y = fmaf(xi, pos ? up.y : un.y, pos ? cp.y : cn.y);
    o.z = fmaf(xi, pos ? up.z : un.z, pos ? cp.z : cn.z);
    o.w = fmaf(xi, pos ? up.w : un.w, pos ? cp.w : cn.w);
    floatx4* dst = (floatx4*)(out + (size_t)(r0 + r) * DM) + t;
    __builtin_nontemporal_store(o, dst);
  }
}

extern "C" void kernel_launch(void* const* d_in, const int* in_sizes, int n_in,
                              void* d_out, int out_size, void* d_ws, size_t ws_size,
                              hipStream_t stream) {
  const float* psiQ = (const float*)d_in[0];
  const float* psiK = (const float*)d_in[1];
  const float* psiV = (const float*)d_in[2];
  const float* W1 = (const float*)d_in[3];
  const float* b1 = (const float*)d_in[4];
  const float* W2 = (const float*)d_in[5];
  const float* b2 = (const float*)d_in[6];
  float* out = (float*)d_out;
  float* ws = (float*)d_ws;

  qac_part<<<64, 256, 0, stream>>>(W1, b1, W2, b2, ws);
  qac_fused<<<NROWS / 64, 256, 0, stream>>>(psiQ, psiK, psiV, ws, out);
}